// Round 2
// baseline (991.215 us; speedup 1.0000x reference)
//
#include <hip/hip_runtime.h>
#include <hip/hip_bf16.h>

#define NN 100000
#define NE 3200000
#define NG 4096

typedef unsigned short ushort_t;

__device__ __forceinline__ float bf2f(unsigned short u){
  union{unsigned int i; float f;} x; x.i = ((unsigned)u)<<16; return x.f;
}
__device__ __forceinline__ ushort_t f2bf(float f){
  union{float f; unsigned int i;} x; x.f = f;
  unsigned int r = x.i + 0x7fff + ((x.i >> 16) & 1);   // round-to-nearest-even
  return (ushort_t)(r >> 16);
}

// ---------------- CSR build ----------------

__global__ __launch_bounds__(256) void k_deg(const int* __restrict__ ei, int* __restrict__ deg){
  int e = blockIdx.x*256 + threadIdx.x;            // grid covers NE exactly
  atomicAdd(&deg[ei[NE + e]], 1);                   // col = ei[NE..2NE)
}

__global__ __launch_bounds__(256) void k_scan1(const int* __restrict__ deg, int* __restrict__ colptr,
                                               int* __restrict__ bsum){
  __shared__ int lds[256];
  int t = threadIdx.x;
  int base = blockIdx.x*1024 + t*4;
  int v0 = (base+0<NN)? deg[base+0]:0;
  int v1 = (base+1<NN)? deg[base+1]:0;
  int v2 = (base+2<NN)? deg[base+2]:0;
  int v3 = (base+3<NN)? deg[base+3]:0;
  int s = v0+v1+v2+v3;
  lds[t] = s; __syncthreads();
  for (int off=1; off<256; off<<=1){
    int x = (t>=off)? lds[t-off]:0;
    __syncthreads();
    lds[t] += x;
    __syncthreads();
  }
  int excl = lds[t]-s;
  if (t==255) bsum[blockIdx.x] = lds[t];
  if (base+0<NN) colptr[base+0]=excl;
  if (base+1<NN) colptr[base+1]=excl+v0;
  if (base+2<NN) colptr[base+2]=excl+v0+v1;
  if (base+3<NN) colptr[base+3]=excl+v0+v1+v2;
}

__global__ void k_scan2(int* __restrict__ bsum){    // 1 block, 128 threads, 98 entries
  __shared__ int lds[128];
  int t = threadIdx.x;
  int s = (t<98)? bsum[t]:0;
  lds[t]=s; __syncthreads();
  for (int off=1; off<128; off<<=1){
    int x=(t>=off)? lds[t-off]:0;
    __syncthreads();
    lds[t]+=x;
    __syncthreads();
  }
  if (t<98) bsum[t] = lds[t]-s;
}

// degcur: deg on input, cursor (== final colptr copy) on output
__global__ __launch_bounds__(256) void k_scan3(const int* __restrict__ bsum, int* __restrict__ colptr,
                                               int* __restrict__ degcur, float* __restrict__ dinv){
  int i = blockIdx.x*256 + threadIdx.x;
  if (i < NN){
    int d  = degcur[i];
    int cp = colptr[i] + bsum[i>>10];
    colptr[i] = cp;
    degcur[i] = cp;
    dinv[i] = rsqrtf((float)d + 1.0f);              // +1 self-loop
  } else if (i == NN){
    colptr[NN] = NE;
  }
}

__global__ __launch_bounds__(256) void k_scatter(const int* __restrict__ ei, int* __restrict__ cursor,
                                                 int* __restrict__ csr){
  int e = blockIdx.x*256 + threadIdx.x;
  int v = ei[NE + e];
  int p = atomicAdd(&cursor[v], 1);
  csr[p] = ei[e];                                   // source node
}

// ---------------- GEMM + dinv scale:  hs = bf16( (h @ W) * dinv[node] ) ----------------

template<int K>
__global__ __launch_bounds__(256) void k_gemm(const float* __restrict__ in_,
    const float* __restrict__ W, const float* __restrict__ dinv,
    ushort_t* __restrict__ out){
  __shared__ float Wl[K*64];
  int t = threadIdx.x;
  for (int i=t; i<K*64; i+=256) Wl[i] = W[i];
  __syncthreads();
  int c  = t & 63;
  int vb = __builtin_amdgcn_readfirstlane((int)(blockIdx.x*16 + (t>>6)*4));
  float acc0=0.f, acc1=0.f, acc2=0.f, acc3=0.f;
  const float4* x0 = (const float4*)(in_ + (size_t)vb*K);
  constexpr int RS = K/4;
  #pragma unroll 4
  for (int k4=0;k4<K/4;++k4){
    float4 a0 = x0[k4], a1 = x0[k4+RS], a2 = x0[k4+2*RS], a3 = x0[k4+3*RS];
    const float* wr = &Wl[k4*4*64 + c];
    float w0=wr[0], w1=wr[64], w2=wr[128], w3=wr[192];
    acc0 = fmaf(a0.x,w0,fmaf(a0.y,w1,fmaf(a0.z,w2,fmaf(a0.w,w3,acc0))));
    acc1 = fmaf(a1.x,w0,fmaf(a1.y,w1,fmaf(a1.z,w2,fmaf(a1.w,w3,acc1))));
    acc2 = fmaf(a2.x,w0,fmaf(a2.y,w1,fmaf(a2.z,w2,fmaf(a2.w,w3,acc2))));
    acc3 = fmaf(a3.x,w0,fmaf(a3.y,w1,fmaf(a3.z,w2,fmaf(a3.w,w3,acc3))));
  }
  float d0=dinv[vb], d1=dinv[vb+1], d2=dinv[vb+2], d3=dinv[vb+3];
  out[(size_t)(vb+0)*64+c]=f2bf(acc0*d0);
  out[(size_t)(vb+1)*64+c]=f2bf(acc1*d1);
  out[(size_t)(vb+2)*64+c]=f2bf(acc2*d2);
  out[(size_t)(vb+3)*64+c]=f2bf(acc3*d3);
}

// ---------------- pull-aggregation + bias + BN-stat partials ----------------
// out[v] = dinv[v]*(hs[v] + sum_{e into v} hs[src_e]) + b ; stats over out

__global__ __launch_bounds__(256) void k_aggregate(const ushort_t* __restrict__ hs,
    const int* __restrict__ colptr, const int* __restrict__ csr,
    const float* __restrict__ dinv, const float* __restrict__ bias,
    float* __restrict__ out, float* __restrict__ stats){
  int t = threadIdx.x; int c = t & 63;
  int wv = blockIdx.x*4 + (t>>6);                   // 8192 waves
  float bc = bias[c];
  float s1 = 0.f, s2 = 0.f;
  for (int v = wv; v < NN; v += 8192){
    int vv = __builtin_amdgcn_readfirstlane(v);
    int e0 = colptr[vv], e1 = colptr[vv+1];
    float acc = bf2f(hs[(size_t)vv*64 + c]);
    int e = e0;
    for (; e+4 <= e1; e += 4){
      int i0=csr[e], i1=csr[e+1], i2=csr[e+2], i3=csr[e+3];
      float f0=bf2f(hs[(size_t)i0*64+c]), f1=bf2f(hs[(size_t)i1*64+c]);
      float f2=bf2f(hs[(size_t)i2*64+c]), f3=bf2f(hs[(size_t)i3*64+c]);
      acc += (f0+f1)+(f2+f3);
    }
    for (; e<e1; ++e) acc += bf2f(hs[(size_t)csr[e]*64+c]);
    float o = acc*dinv[vv] + bc;
    out[(size_t)vv*64+c] = o;
    s1 += o; s2 += o*o;
  }
  __shared__ float l1[256], l2[256];
  l1[t]=s1; l2[t]=s2; __syncthreads();
  if (t < 64){
    float a1 = l1[t]+l1[t+64]+l1[t+128]+l1[t+192];
    float a2 = l2[t]+l2[t+64]+l2[t+128]+l2[t+192];
    float* rep = stats + (size_t)(blockIdx.x & 31)*128;
    atomicAdd(&rep[t],    a1);
    atomicAdd(&rep[64+t], a2);
  }
}

// ---------------- BN coeff + apply ----------------

__global__ void k_bncoeff(const float* __restrict__ stats, const float* __restrict__ g,
                          const float* __restrict__ be, float cnt, float* __restrict__ coeff){
  int c = threadIdx.x;                               // 64 threads
  float s1=0.f, s2=0.f;
  for (int r=0;r<32;++r){ s1 += stats[r*128+c]; s2 += stats[r*128+64+c]; }
  float mu  = s1/cnt;
  float var = s2/cnt - mu*mu;
  float a   = g[c]*rsqrtf(var + 1e-5f);
  coeff[c]    = a;
  coeff[64+c] = be[c] - mu*a;
}

__global__ __launch_bounds__(256) void k_bnapply(float* __restrict__ buf, const float* __restrict__ cf){
  int i = blockIdx.x*256 + threadIdx.x;              // NN*64/4 quads
  float4 v = ((float4*)buf)[i];
  int c0 = (i & 15)*4;
  float a0=cf[c0+0], a1=cf[c0+1], a2=cf[c0+2], a3=cf[c0+3];
  float d0=cf[64+c0+0], d1=cf[64+c0+1], d2=cf[64+c0+2], d3=cf[64+c0+3];
  v.x = fmaxf(fmaf(v.x,a0,d0),0.f);
  v.y = fmaxf(fmaf(v.y,a1,d1),0.f);
  v.z = fmaxf(fmaf(v.z,a2,d2),0.f);
  v.w = fmaxf(fmaf(v.w,a3,d3),0.f);
  ((float4*)buf)[i] = v;
}

// ---------------- pooling / head ----------------

__global__ __launch_bounds__(256) void k_gbounds(const int* __restrict__ batch, int* __restrict__ gstart){
  int g = blockIdx.x*256 + threadIdx.x;              // 4096
  int lo=0, hi=NN;
  while (lo<hi){ int mid=(lo+hi)>>1; if (batch[mid]<g) lo=mid+1; else hi=mid; }
  gstart[g]=lo;
  if (g==0) gstart[NG]=NN;
}

__global__ __launch_bounds__(256) void k_pool(const float* __restrict__ h, const int* __restrict__ gstart,
                                              float* __restrict__ pooled){
  int t=threadIdx.x; int c=t&63;
  int g = __builtin_amdgcn_readfirstlane((int)(blockIdx.x*4 + (t>>6)));
  int s = gstart[g], e = gstart[g+1];
  float acc=0.f;
  for (int v=s; v<e; ++v) acc += h[(size_t)v*64+c];
  float inv = 1.0f / fmaxf((float)(e-s), 1.0f);
  pooled[(size_t)g*64+c] = acc*inv;
}

__global__ __launch_bounds__(256) void k_tkern(float* __restrict__ pooled, const float* __restrict__ W1,
                                               const float* __restrict__ b1, float* __restrict__ stats){
  int t=threadIdx.x; int c=t&63;
  int g = __builtin_amdgcn_readfirstlane((int)(blockIdx.x*4 + (t>>6)));
  const float* p = pooled + (size_t)g*64;
  float acc = b1[c];
  #pragma unroll 4
  for (int k=0;k<64;++k) acc = fmaf(p[k], W1[k*64+c], acc);
  pooled[(size_t)g*64+c] = acc;                      // in-place: t
  float* rep = stats + (size_t)(blockIdx.x & 31)*128;
  atomicAdd(&rep[c],    acc);
  atomicAdd(&rep[64+c], acc*acc);
}

__global__ __launch_bounds__(256) void k_final(const float* __restrict__ tbuf, const float* __restrict__ gcf,
                                               const float* __restrict__ W2, const float* __restrict__ b2,
                                               float* __restrict__ out){
  int t=threadIdx.x; int c=t&63;
  int g = blockIdx.x*4 + (t>>6);
  float tv = tbuf[(size_t)g*64+c];
  float z  = fmaxf(fmaf(tv, gcf[c], gcf[64+c]), 0.f);
  float p  = z * W2[c];
  #pragma unroll
  for (int o=32;o>0;o>>=1) p += __shfl_xor(p, o, 64);
  if (c==0) out[g] = p + b2[0];
}

// ---------------- launch ----------------

extern "C" void kernel_launch(void* const* d_in, const int* in_sizes, int n_in,
                              void* d_out, int out_size, void* d_ws, size_t ws_size,
                              hipStream_t stream) {
  const float* x    = (const float*)d_in[0];
  const int*   ei   = (const int*)d_in[1];
  const int*   batch= (const int*)d_in[2];
  const float* Wc0=(const float*)d_in[3],  *bc0=(const float*)d_in[4];
  const float* g0 =(const float*)d_in[5],  *be0=(const float*)d_in[6];
  const float* Wc1=(const float*)d_in[7],  *bc1=(const float*)d_in[8];
  const float* g1 =(const float*)d_in[9],  *be1=(const float*)d_in[10];
  const float* Wc2=(const float*)d_in[11], *bc2=(const float*)d_in[12];
  const float* g2 =(const float*)d_in[13], *be2=(const float*)d_in[14];
  const float* W1 =(const float*)d_in[15], *b1 =(const float*)d_in[16];
  const float* gf =(const float*)d_in[17], *bf_=(const float*)d_in[18];
  const float* W2 =(const float*)d_in[19], *b2 =(const float*)d_in[20];
  float* out = (float*)d_out;

  char* w = (char*)d_ws;
  // zeroed region: [stats 65536][deg 400000]
  float*    stats  = (float*)   (w + 0);             // 4 sets x 32 reps x 128 f
  int*      deg    = (int*)     (w + 65536);         // also cursor
  int*      colptr = (int*)     (w + 465536);        // NN+1
  float*    dinv   = (float*)   (w + 865552);
  int*      gstart = (int*)     (w + 1265552);       // NG+1
  float*    coeff  = (float*)   (w + 1281952);       // a[64], d[64]
  float*    gcoeff = (float*)   (w + 1282464);
  float*    pooled = (float*)   (w + 1282976);       // NG x 64
  int*      csr    = (int*)     (w + 2331552);       // NE
  ushort_t* bufA   = (ushort_t*)(w + 15131552);      // hs (bf16), NN x 64
  float*    bufB   = (float*)   (w + 27931552);      // pre-BN / h (fp32), ends 53.5 MB

  int* bsum = (int*)pooled;                          // pooled dead until after CSR build

  hipMemsetAsync(w, 0, 465536, stream);

  k_deg    <<<NE/256, 256, 0, stream>>>(ei, deg);
  k_scan1  <<<98,     256, 0, stream>>>(deg, colptr, bsum);
  k_scan2  <<<1,      128, 0, stream>>>(bsum);
  k_scan3  <<<391,    256, 0, stream>>>(bsum, colptr, deg, dinv);
  k_scatter<<<NE/256, 256, 0, stream>>>(ei, deg, csr);

  // layer 0
  k_gemm<128><<<NN/16, 256, 0, stream>>>(x, Wc0, dinv, bufA);
  k_aggregate<<<2048, 256, 0, stream>>>(bufA, colptr, csr, dinv, bc0, bufB, stats + 0*4096);
  k_bncoeff<<<1, 64, 0, stream>>>(stats + 0*4096, g0, be0, (float)NN, coeff);
  k_bnapply<<<NN*16/256, 256, 0, stream>>>(bufB, coeff);
  // layer 1
  k_gemm<64><<<NN/16, 256, 0, stream>>>(bufB, Wc1, dinv, bufA);
  k_aggregate<<<2048, 256, 0, stream>>>(bufA, colptr, csr, dinv, bc1, bufB, stats + 1*4096);
  k_bncoeff<<<1, 64, 0, stream>>>(stats + 1*4096, g1, be1, (float)NN, coeff);
  k_bnapply<<<NN*16/256, 256, 0, stream>>>(bufB, coeff);
  // layer 2
  k_gemm<64><<<NN/16, 256, 0, stream>>>(bufB, Wc2, dinv, bufA);
  k_aggregate<<<2048, 256, 0, stream>>>(bufA, colptr, csr, dinv, bc2, bufB, stats + 2*4096);
  k_bncoeff<<<1, 64, 0, stream>>>(stats + 2*4096, g2, be2, (float)NN, coeff);
  k_bnapply<<<NN*16/256, 256, 0, stream>>>(bufB, coeff);

  // head
  k_gbounds<<<NG/256, 256, 0, stream>>>(batch, gstart);
  k_pool   <<<NG/4,   256, 0, stream>>>(bufB, gstart, pooled);
  k_tkern  <<<NG/4,   256, 0, stream>>>(pooled, W1, b1, stats + 3*4096);
  k_bncoeff<<<1, 64, 0, stream>>>(stats + 3*4096, gf, bf_, (float)NG, gcoeff);
  k_final  <<<NG/4,   256, 0, stream>>>(pooled, gcoeff, W2, b2, out);
}

// Round 3
// 674.190 us; speedup vs baseline: 1.4702x; 1.4702x over previous
//
#include <hip/hip_runtime.h>
#include <hip/hip_bf16.h>

#define NN 100000
#define NE 3200000
#define NG 4096
#define NB 128          // blocks in hist/pairs pass; NE/NB = 25000 exactly
#define NBK 782         // coarse buckets of 128 nodes: 781*128+32 = 100000

typedef unsigned short ushort_t;

__device__ __forceinline__ float bf2f(unsigned short u){
  union{unsigned int i; float f;} x; x.i = ((unsigned)u)<<16; return x.f;
}
__device__ __forceinline__ ushort_t f2bf(float f){
  union{float f; unsigned int i;} x; x.f = f;
  unsigned int r = x.i + 0x7fff + ((x.i >> 16) & 1);   // round-to-nearest-even
  return (ushort_t)(r >> 16);
}

// ---------------- CSR build: hierarchical counting sort ----------------

__global__ __launch_bounds__(256) void k_hist(const int* __restrict__ ei, int* __restrict__ histT){
  __shared__ int lh[NBK];
  int b = blockIdx.x, t = threadIdx.x;
  for (int k=t; k<NBK; k+=256) lh[k]=0;
  __syncthreads();
  int e0 = b*(NE/NB);
  for (int e=e0+t; e<e0+(NE/NB); e+=256) atomicAdd(&lh[ei[NE+e]>>7], 1);
  __syncthreads();
  for (int k=t; k<NBK; k+=256) histT[k*NB+b] = lh[k];
}

// one wave per bucket: exclusive scan of the 128 per-block counts; total per bucket
__global__ __launch_bounds__(256) void k_scanA(int* __restrict__ histT, int* __restrict__ total){
  int wv = blockIdx.x*4 + (threadIdx.x>>6);
  int lane = threadIdx.x & 63;
  if (wv >= NBK) return;                         // wave-uniform exit
  int* row = histT + wv*NB;
  int a0 = row[lane], a1 = row[64+lane];
  int i0 = a0, i1 = a1;
  for (int off=1; off<64; off<<=1){
    int x = __shfl_up(i0, off, 64);
    int y = __shfl_up(i1, off, 64);
    if (lane >= off){ i0 += x; i1 += y; }
  }
  i1 += __shfl(i0, 63, 64);
  row[lane]    = i0 - a0;
  row[64+lane] = i1 - a1;
  if (lane==63) total[wv] = i1;
}

__global__ void k_scanB(const int* __restrict__ total, int* __restrict__ base){
  __shared__ int lds[1024];
  int t = threadIdx.x;
  int v = (t < NBK)? total[t] : 0;
  lds[t] = v; __syncthreads();
  for (int off=1; off<1024; off<<=1){
    int x = (t>=off)? lds[t-off] : 0;
    __syncthreads();
    lds[t] += x;
    __syncthreads();
  }
  if (t < NBK)      base[t]   = lds[t]-v;        // exclusive
  if (t == NBK-1)   base[NBK] = lds[t];          // == NE
}

// stable partition into bucket regions; packed token (src<<7)|(dst&127)
__global__ __launch_bounds__(256) void k_pairs(const int* __restrict__ ei,
    const int* __restrict__ histT, const int* __restrict__ base,
    int* __restrict__ pairs){
  __shared__ int cur[NBK];
  int b = blockIdx.x, t = threadIdx.x;
  for (int k=t; k<NBK; k+=256) cur[k] = base[k] + histT[k*NB + b];
  __syncthreads();
  int e0 = b*(NE/NB);
  for (int e=e0+t; e<e0+(NE/NB); e+=256){
    int src = ei[e], dst = ei[NE+e];
    int p = atomicAdd(&cur[dst>>7], 1);          // LDS atomic
    pairs[p] = (src << 7) | (dst & 127);
  }
}

// per-bucket 7-bit counting sort -> csr (src order per dest node); also colptr, dinv
__global__ __launch_bounds__(256) void k_fine(const int* __restrict__ pairs,
    const int* __restrict__ base, int* __restrict__ csr,
    int* __restrict__ colptr, float* __restrict__ dinv){
  __shared__ int cnt[128], off[128];
  int k = blockIdx.x, t = threadIdx.x;
  if (t < 128) cnt[t] = 0;
  __syncthreads();
  int s = base[k], e = base[k+1];
  for (int i=s+t; i<e; i+=256) atomicAdd(&cnt[pairs[i] & 127], 1);
  __syncthreads();
  int v = (t<128)? cnt[t] : 0;
  if (t<128) off[t] = v;
  __syncthreads();
  for (int o=1; o<128; o<<=1){
    int x = (t>=o && t<128)? off[t-o] : 0;
    __syncthreads();
    if (t<128) off[t] += x;
    __syncthreads();
  }
  int node0 = k*128;
  if (t < 128 && node0+t < NN){
    colptr[node0+t] = s + off[t] - v;            // exclusive within bucket
    dinv[node0+t]   = rsqrtf((float)cnt[t] + 1.0f);  // +1 self-loop
  }
  if (k == NBK-1 && t == 0) colptr[NN] = NE;
  __syncthreads();
  if (t < 128) cnt[t] = off[t] - v;              // cursors
  __syncthreads();
  for (int i=s+t; i<e; i+=256){
    int u = pairs[i];
    int p = s + atomicAdd(&cnt[u & 127], 1);     // LDS atomic, bucket-local write
    csr[p] = u >> 7;
  }
}

// ---------------- GEMM + dinv scale:  hs = bf16( (h @ W) * dinv[node] ) ----------------

template<int K>
__global__ __launch_bounds__(256) void k_gemm(const float* __restrict__ in_,
    const float* __restrict__ W, const float* __restrict__ dinv,
    ushort_t* __restrict__ out){
  __shared__ float Wl[K*64];
  int t = threadIdx.x;
  for (int i=t; i<K*64; i+=256) Wl[i] = W[i];
  __syncthreads();
  int c  = t & 63;
  int vb = __builtin_amdgcn_readfirstlane((int)(blockIdx.x*16 + (t>>6)*4));
  float acc0=0.f, acc1=0.f, acc2=0.f, acc3=0.f;
  const float4* x0 = (const float4*)(in_ + (size_t)vb*K);
  constexpr int RS = K/4;
  #pragma unroll 4
  for (int k4=0;k4<K/4;++k4){
    float4 a0 = x0[k4], a1 = x0[k4+RS], a2 = x0[k4+2*RS], a3 = x0[k4+3*RS];
    const float* wr = &Wl[k4*4*64 + c];
    float w0=wr[0], w1=wr[64], w2=wr[128], w3=wr[192];
    acc0 = fmaf(a0.x,w0,fmaf(a0.y,w1,fmaf(a0.z,w2,fmaf(a0.w,w3,acc0))));
    acc1 = fmaf(a1.x,w0,fmaf(a1.y,w1,fmaf(a1.z,w2,fmaf(a1.w,w3,acc1))));
    acc2 = fmaf(a2.x,w0,fmaf(a2.y,w1,fmaf(a2.z,w2,fmaf(a2.w,w3,acc2))));
    acc3 = fmaf(a3.x,w0,fmaf(a3.y,w1,fmaf(a3.z,w2,fmaf(a3.w,w3,acc3))));
  }
  float d0=dinv[vb], d1=dinv[vb+1], d2=dinv[vb+2], d3=dinv[vb+3];
  out[(size_t)(vb+0)*64+c]=f2bf(acc0*d0);
  out[(size_t)(vb+1)*64+c]=f2bf(acc1*d1);
  out[(size_t)(vb+2)*64+c]=f2bf(acc2*d2);
  out[(size_t)(vb+3)*64+c]=f2bf(acc3*d3);
}

// ---------------- pull-aggregation + bias + BN-stat partials ----------------

__global__ __launch_bounds__(256) void k_aggregate(const ushort_t* __restrict__ hs,
    const int* __restrict__ colptr, const int* __restrict__ csr,
    const float* __restrict__ dinv, const float* __restrict__ bias,
    float* __restrict__ out, float* __restrict__ stats){
  int t = threadIdx.x; int c = t & 63;
  int wv = blockIdx.x*4 + (t>>6);                // 8192 waves
  float bc = bias[c];
  float s1 = 0.f, s2 = 0.f;
  for (int v = wv; v < NN; v += 8192){
    int vv = __builtin_amdgcn_readfirstlane(v);
    int e0 = colptr[vv], e1 = colptr[vv+1];
    float acc = bf2f(hs[(size_t)vv*64 + c]);
    int e = e0;
    for (; e+4 <= e1; e += 4){
      int i0=csr[e], i1=csr[e+1], i2=csr[e+2], i3=csr[e+3];
      float f0=bf2f(hs[(size_t)i0*64+c]), f1=bf2f(hs[(size_t)i1*64+c]);
      float f2=bf2f(hs[(size_t)i2*64+c]), f3=bf2f(hs[(size_t)i3*64+c]);
      acc += (f0+f1)+(f2+f3);
    }
    for (; e<e1; ++e) acc += bf2f(hs[(size_t)csr[e]*64+c]);
    float o = acc*dinv[vv] + bc;
    out[(size_t)vv*64+c] = o;
    s1 += o; s2 += o*o;
  }
  __shared__ float l1[256], l2[256];
  l1[t]=s1; l2[t]=s2; __syncthreads();
  if (t < 64){
    float a1 = l1[t]+l1[t+64]+l1[t+128]+l1[t+192];
    float a2 = l2[t]+l2[t+64]+l2[t+128]+l2[t+192];
    float* rep = stats + (size_t)(blockIdx.x & 31)*128;
    atomicAdd(&rep[t],    a1);
    atomicAdd(&rep[64+t], a2);
  }
}

// ---------------- BN coeff + apply ----------------

__global__ void k_bncoeff(const float* __restrict__ stats, const float* __restrict__ g,
                          const float* __restrict__ be, float cnt, float* __restrict__ coeff){
  int c = threadIdx.x;                           // 64 threads
  float s1=0.f, s2=0.f;
  for (int r=0;r<32;++r){ s1 += stats[r*128+c]; s2 += stats[r*128+64+c]; }
  float mu  = s1/cnt;
  float var = s2/cnt - mu*mu;
  float a   = g[c]*rsqrtf(var + 1e-5f);
  coeff[c]    = a;
  coeff[64+c] = be[c] - mu*a;
}

__global__ __launch_bounds__(256) void k_bnapply(float* __restrict__ buf, const float* __restrict__ cf){
  int i = blockIdx.x*256 + threadIdx.x;          // NN*64/4 quads
  float4 v = ((float4*)buf)[i];
  int c0 = (i & 15)*4;
  float a0=cf[c0+0], a1=cf[c0+1], a2=cf[c0+2], a3=cf[c0+3];
  float d0=cf[64+c0+0], d1=cf[64+c0+1], d2=cf[64+c0+2], d3=cf[64+c0+3];
  v.x = fmaxf(fmaf(v.x,a0,d0),0.f);
  v.y = fmaxf(fmaf(v.y,a1,d1),0.f);
  v.z = fmaxf(fmaf(v.z,a2,d2),0.f);
  v.w = fmaxf(fmaf(v.w,a3,d3),0.f);
  ((float4*)buf)[i] = v;
}

// ---------------- pooling / head ----------------

__global__ __launch_bounds__(256) void k_gbounds(const int* __restrict__ batch, int* __restrict__ gstart){
  int g = blockIdx.x*256 + threadIdx.x;          // 4096
  int lo=0, hi=NN;
  while (lo<hi){ int mid=(lo+hi)>>1; if (batch[mid]<g) lo=mid+1; else hi=mid; }
  gstart[g]=lo;
  if (g==0) gstart[NG]=NN;
}

__global__ __launch_bounds__(256) void k_pool(const float* __restrict__ h, const int* __restrict__ gstart,
                                              float* __restrict__ pooled){
  int t=threadIdx.x; int c=t&63;
  int g = __builtin_amdgcn_readfirstlane((int)(blockIdx.x*4 + (t>>6)));
  int s = gstart[g], e = gstart[g+1];
  float acc=0.f;
  for (int v=s; v<e; ++v) acc += h[(size_t)v*64+c];
  float inv = 1.0f / fmaxf((float)(e-s), 1.0f);
  pooled[(size_t)g*64+c] = acc*inv;
}

__global__ __launch_bounds__(256) void k_tkern(float* __restrict__ pooled, const float* __restrict__ W1,
                                               const float* __restrict__ b1, float* __restrict__ stats){
  int t=threadIdx.x; int c=t&63;
  int g = __builtin_amdgcn_readfirstlane((int)(blockIdx.x*4 + (t>>6)));
  const float* p = pooled + (size_t)g*64;
  float acc = b1[c];
  #pragma unroll 4
  for (int k=0;k<64;++k) acc = fmaf(p[k], W1[k*64+c], acc);
  pooled[(size_t)g*64+c] = acc;
  float* rep = stats + (size_t)(blockIdx.x & 31)*128;
  atomicAdd(&rep[c],    acc);
  atomicAdd(&rep[64+c], acc*acc);
}

__global__ __launch_bounds__(256) void k_final(const float* __restrict__ tbuf, const float* __restrict__ gcf,
                                               const float* __restrict__ W2, const float* __restrict__ b2,
                                               float* __restrict__ out){
  int t=threadIdx.x; int c=t&63;
  int g = blockIdx.x*4 + (t>>6);
  float tv = tbuf[(size_t)g*64+c];
  float z  = fmaxf(fmaf(tv, gcf[c], gcf[64+c]), 0.f);
  float p  = z * W2[c];
  #pragma unroll
  for (int o=32;o>0;o>>=1) p += __shfl_xor(p, o, 64);
  if (c==0) out[g] = p + b2[0];
}

// ---------------- launch ----------------

extern "C" void kernel_launch(void* const* d_in, const int* in_sizes, int n_in,
                              void* d_out, int out_size, void* d_ws, size_t ws_size,
                              hipStream_t stream) {
  const float* x    = (const float*)d_in[0];
  const int*   ei   = (const int*)d_in[1];
  const int*   batch= (const int*)d_in[2];
  const float* Wc0=(const float*)d_in[3],  *bc0=(const float*)d_in[4];
  const float* g0 =(const float*)d_in[5],  *be0=(const float*)d_in[6];
  const float* Wc1=(const float*)d_in[7],  *bc1=(const float*)d_in[8];
  const float* g1 =(const float*)d_in[9],  *be1=(const float*)d_in[10];
  const float* Wc2=(const float*)d_in[11], *bc2=(const float*)d_in[12];
  const float* g2 =(const float*)d_in[13], *be2=(const float*)d_in[14];
  const float* W1 =(const float*)d_in[15], *b1 =(const float*)d_in[16];
  const float* gf =(const float*)d_in[17], *bf_=(const float*)d_in[18];
  const float* W2 =(const float*)d_in[19], *b2 =(const float*)d_in[20];
  float* out = (float*)d_out;

  char* w = (char*)d_ws;
  float*    stats  = (float*)   (w + 0);         // 4 sets x 32 reps x 128 f  [zeroed]
  int*      histT  = (int*)     (w + 65536);     // NBK x NB ints = 400,384 B
  int*      total  = (int*)     (w + 465920);    // NBK
  int*      base   = (int*)     (w + 469056);    // NBK+1
  int*      colptr = (int*)     (w + 472192);    // NN+1
  float*    dinv   = (float*)   (w + 872208);
  int*      gstart = (int*)     (w + 1272208);   // NG+1
  float*    coeff  = (float*)   (w + 1288608);   // a[64], d[64]
  float*    gcoeff = (float*)   (w + 1289120);
  float*    pooled = (float*)   (w + 1289632);   // NG x 64
  int*      csr    = (int*)     (w + 2338240);   // NE ints
  ushort_t* bufA   = (ushort_t*)(w + 15138240);  // hs (bf16), NN x 64
  float*    bufB   = (float*)   (w + 27938240);  // pre-BN / h (fp32); ends ~53.5 MB
  int*      pairs  = (int*)bufB;                 // alias: dead before bufB first write

  hipMemsetAsync(stats, 0, 65536, stream);

  // CSR build (no global atomics)
  k_hist <<<NB,  256,  0, stream>>>(ei, histT);
  k_scanA<<<196, 256,  0, stream>>>(histT, total);
  k_scanB<<<1,   1024, 0, stream>>>(total, base);
  k_pairs<<<NB,  256,  0, stream>>>(ei, histT, base, pairs);
  k_fine <<<NBK, 256,  0, stream>>>(pairs, base, csr, colptr, dinv);

  // layer 0
  k_gemm<128><<<NN/16, 256, 0, stream>>>(x, Wc0, dinv, bufA);
  k_aggregate<<<2048, 256, 0, stream>>>(bufA, colptr, csr, dinv, bc0, bufB, stats + 0*4096);
  k_bncoeff<<<1, 64, 0, stream>>>(stats + 0*4096, g0, be0, (float)NN, coeff);
  k_bnapply<<<NN*16/256, 256, 0, stream>>>(bufB, coeff);
  // layer 1
  k_gemm<64><<<NN/16, 256, 0, stream>>>(bufB, Wc1, dinv, bufA);
  k_aggregate<<<2048, 256, 0, stream>>>(bufA, colptr, csr, dinv, bc1, bufB, stats + 1*4096);
  k_bncoeff<<<1, 64, 0, stream>>>(stats + 1*4096, g1, be1, (float)NN, coeff);
  k_bnapply<<<NN*16/256, 256, 0, stream>>>(bufB, coeff);
  // layer 2
  k_gemm<64><<<NN/16, 256, 0, stream>>>(bufB, Wc2, dinv, bufA);
  k_aggregate<<<2048, 256, 0, stream>>>(bufA, colptr, csr, dinv, bc2, bufB, stats + 2*4096);
  k_bncoeff<<<1, 64, 0, stream>>>(stats + 2*4096, g2, be2, (float)NN, coeff);
  k_bnapply<<<NN*16/256, 256, 0, stream>>>(bufB, coeff);

  // head
  k_gbounds<<<NG/256, 256, 0, stream>>>(batch, gstart);
  k_pool   <<<NG/4,   256, 0, stream>>>(bufB, gstart, pooled);
  k_tkern  <<<NG/4,   256, 0, stream>>>(pooled, W1, b1, stats + 3*4096);
  k_bncoeff<<<1, 64, 0, stream>>>(stats + 3*4096, gf, bf_, (float)NG, gcoeff);
  k_final  <<<NG/4,   256, 0, stream>>>(pooled, gcoeff, W2, b2, out);
}